// Round 5
// baseline (1113.065 us; speedup 1.0000x reference)
//
#include <hip/hip_runtime.h>
#include <hip/hip_fp16.h>
#include <hip/hip_fp8.h>

#define N_NODES 100000
#define N_EDGES 1600000
#define ET      (N_EDGES + N_NODES)   // 1,700,000
#define NG      512
#define SLOPE   0.2f

#define FBK_SHIFT 7                         // 128 nodes per fine bucket
#define NB_F   ((N_NODES + 127) / 128)      // 782 fine buckets
#define BCAP_F 2944                         // mean 2176, sigma~45 -> +17 sigma
#define CHUNK_A 8192
#define NBLK_A ((ET + CHUNK_A - 1) / CHUNK_A)   // 208
#define H1B4   ((N_NODES + 1023) / 1024)        // 98 mfma blocks (1024 nodes each)

#define AS1 69   // agg1 LDS row stride: 64 ch + 4 den + pad (bank spread: 5*dl+c)
#define AS2 21   // agg2 LDS row stride: 16 ch + 1 den + pad

typedef _Float16 half8_t __attribute__((ext_vector_type(8)));
typedef float    f32x4_t __attribute__((ext_vector_type(4)));
typedef float    f32x2_t __attribute__((ext_vector_type(2)));

// ---- fused: [sort role] LDS counting sort into 128-node fine buckets
//      [prep role]  MFMA h1 = x@W1 (fp8 out) + layer-1 logits ----
__global__ __launch_bounds__(1024) void k_prepA(
    const float* __restrict__ x, const float* __restrict__ W1,
    const float* __restrict__ a1s, const float* __restrict__ a1d,
    const int* __restrict__ ei,
    int* __restrict__ gcnt, unsigned int* __restrict__ ebuf,
    __hip_fp8_e4m3* __restrict__ h1, float* __restrict__ al1s, float* __restrict__ al1d)
{
    __shared__ union U {
        struct { float Wl[64 * 64]; float asf[64]; float adf[64]; } p;       // 16.9 KB
        struct {
            union { unsigned int stage[CHUNK_A]; int tmp[1024]; } s;         // 32 KB (tmp used pre-stage)
            unsigned short sbin[CHUNK_A];                                    // 16 KB
            int hist[NB_F]; int binst[NB_F]; int resv[NB_F]; int cur[NB_F];  // 12.5 KB
        } a;                                                                 // 60.2 KB
    } u;
    int tid = threadIdx.x;

    if (blockIdx.x < NBLK_A) {
        // ---------------- sort role: 8K-edge chunk -> fine buckets ----------------
        int base = blockIdx.x * CHUNK_A;
        int m = min(CHUNK_A, ET - base);
        for (int i = tid; i < NB_F; i += 1024) u.a.hist[i] = 0;
        __syncthreads();
        for (int i = tid; i < m; i += 1024) {
            int eid = base + i;
            int d = (eid < N_EDGES) ? ei[N_EDGES + eid] : (eid - N_EDGES);
            atomicAdd(&u.a.hist[d >> FBK_SHIFT], 1);
        }
        __syncthreads();
        int v = (tid < NB_F) ? u.a.hist[tid] : 0;
        u.a.s.tmp[tid] = v;          // tmp aliases stage: stage not yet written
        __syncthreads();
        for (int off = 1; off < 1024; off <<= 1) {
            int t = (tid >= off) ? u.a.s.tmp[tid - off] : 0;
            __syncthreads();
            u.a.s.tmp[tid] += t;
            __syncthreads();
        }
        if (tid < NB_F) {
            int e = u.a.s.tmp[tid] - v;
            u.a.binst[tid] = e;
            u.a.cur[tid] = e;
            u.a.resv[tid] = v ? atomicAdd(&gcnt[tid], v) : 0;  // offset within fixed bucket
        }
        __syncthreads();
        for (int i = tid; i < m; i += 1024) {
            int eid = base + i;
            int s, d;
            if (eid < N_EDGES) { s = ei[eid]; d = ei[N_EDGES + eid]; }
            else               { s = eid - N_EDGES; d = s; }
            int b = d >> FBK_SHIFT;
            int pos = atomicAdd(&u.a.cur[b], 1);
            u.a.s.stage[pos] = ((unsigned int)(d & 127) << 17) | (unsigned int)s;
            u.a.sbin[pos] = (unsigned short)b;
        }
        __syncthreads();
        for (int i = tid; i < m; i += 1024) {
            int b = u.a.sbin[i];
            int dst = u.a.resv[b] + (i - u.a.binst[b]);
            if (dst < BCAP_F)                      // hard OOB guard (stat. unreachable)
                ebuf[b * BCAP_F + dst] = u.a.s.stage[i];
        }
        return;
    }

    // ---------------- prep role: 16 waves x 16 nodes x 4 iters = 1024 nodes ----------------
    for (int i = tid; i < 64 * 64; i += 1024) u.p.Wl[i] = W1[i];
    if (tid < 64) { u.p.asf[tid] = a1s[tid]; u.p.adf[tid] = a1d[tid]; }
    __syncthreads();

    int wv = tid >> 6, lane = tid & 63;
    int m = lane & 15, q = lane >> 4;

    half8_t bf[4][2];
#pragma unroll
    for (int t = 0; t < 4; ++t)
#pragma unroll
        for (int s = 0; s < 2; ++s) {
            half8_t b;
#pragma unroll
            for (int j = 0; j < 8; ++j)
                b[j] = (_Float16)u.p.Wl[(s * 32 + q * 8 + j) * 64 + t * 16 + m];
            bf[t][s] = b;
        }

    int nodebase = (blockIdx.x - NBLK_A) * 1024 + wv * 64;
    for (int it = 0; it < 4; ++it) {
        int node0 = nodebase + it * 16;
        int node = node0 + m;
        half8_t av0 = {}, av1 = {};
        if (node < N_NODES) {
            const float4* xr = (const float4*)(x + (long long)node * 64);
            float4 p0 = xr[q * 2], p1 = xr[q * 2 + 1];
            float4 p2 = xr[q * 2 + 8], p3 = xr[q * 2 + 9];
            av0[0] = (_Float16)p0.x; av0[1] = (_Float16)p0.y;
            av0[2] = (_Float16)p0.z; av0[3] = (_Float16)p0.w;
            av0[4] = (_Float16)p1.x; av0[5] = (_Float16)p1.y;
            av0[6] = (_Float16)p1.z; av0[7] = (_Float16)p1.w;
            av1[0] = (_Float16)p2.x; av1[1] = (_Float16)p2.y;
            av1[2] = (_Float16)p2.z; av1[3] = (_Float16)p2.w;
            av1[4] = (_Float16)p3.x; av1[5] = (_Float16)p3.y;
            av1[6] = (_Float16)p3.z; av1[7] = (_Float16)p3.w;
        }
        f32x4_t acc[4] = {{0,0,0,0},{0,0,0,0},{0,0,0,0},{0,0,0,0}};
#pragma unroll
        for (int t = 0; t < 4; ++t) {
            acc[t] = __builtin_amdgcn_mfma_f32_16x16x32_f16(av0, bf[t][0], acc[t], 0, 0, 0);
            acc[t] = __builtin_amdgcn_mfma_f32_16x16x32_f16(av1, bf[t][1], acc[t], 0, 0, 0);
        }
#pragma unroll
        for (int r = 0; r < 4; ++r) {
            int nr = node0 + q * 4 + r;
            bool ok = nr < N_NODES;
#pragma unroll
            for (int t = 0; t < 4; ++t) {
                float v = acc[t][r];
                if (ok) h1[(long long)nr * 64 + t * 16 + m] = __hip_fp8_e4m3(v);
                float ps = v * u.p.asf[t * 16 + m];
                float pd = v * u.p.adf[t * 16 + m];
                ps += __shfl_xor(ps, 1); ps += __shfl_xor(ps, 2);
                ps += __shfl_xor(ps, 4); ps += __shfl_xor(ps, 8);
                pd += __shfl_xor(pd, 1); pd += __shfl_xor(pd, 2);
                pd += __shfl_xor(pd, 4); pd += __shfl_xor(pd, 8);
                if (ok && m == t) { al1s[nr * 4 + t] = ps; al1d[nr * 4 + t] = pd; }
            }
        }
    }
}

// ---- layer 1 aggregate: edge-parallel, LDS atomic accumulators per 128-node bucket ----
__global__ __launch_bounds__(256) void k_agg1(
    const unsigned int* __restrict__ ebuf, const int* __restrict__ gcnt,
    const __hip_fp8_e4m3* __restrict__ h1,
    const float* __restrict__ al1s, const float* __restrict__ al1d,
    const float* __restrict__ b1, __half* __restrict__ h1bg)
{
    __shared__ float acc[128 * AS1];    // 35.3 KB: [dl][0..63]=ch, [64..67]=den per head
    int tid = threadIdx.x;
    int b = blockIdx.x;
    int nb0 = b << FBK_SHIFT;
    int nn = min(128, N_NODES - nb0);
    int cnt = min(gcnt[b], BCAP_F);     // clamped (matches write guard)
    for (int i = tid; i < 128 * AS1; i += 256) acc[i] = 0.f;
    __syncthreads();

    const float4* __restrict__ as4p = (const float4*)al1s;
    const float4* __restrict__ ad4p = (const float4*)al1d;
    const uint4*  __restrict__ h1v  = (const uint4*)h1;   // 16 fp8 per uint4

    for (int i = tid; i < cnt; i += 256) {
        unsigned int ev = ebuf[b * BCAP_F + i];           // coalesced
        int s  = (int)(ev & 0x1FFFF);
        int dl = (int)(ev >> 17);
        float4 as4 = as4p[s];                             // 16B gather (L2/L3)
        float4 ad4 = ad4p[nb0 + dl];                      // 16B gather (L1-hot, 128 rows)
        float e0 = as4.x + ad4.x; e0 = e0 > 0.f ? e0 : SLOPE * e0;
        float e1 = as4.y + ad4.y; e1 = e1 > 0.f ? e1 : SLOPE * e1;
        float e2 = as4.z + ad4.z; e2 = e2 > 0.f ? e2 : SLOPE * e2;
        float e3 = as4.w + ad4.w; e3 = e3 > 0.f ? e3 : SLOPE * e3;
        float w[4] = {__expf(e0), __expf(e1), __expf(e2), __expf(e3)};
        float* ap = acc + dl * AS1;
#pragma unroll
        for (int t = 0; t < 4; ++t) {
            uint4 r = h1v[s * 4 + t];                     // channels 16t..16t+15 (fp8)
            float wt = w[t];
            unsigned int dw[4] = {r.x, r.y, r.z, r.w};
#pragma unroll
            for (int k = 0; k < 4; ++k) {
                f32x2_t lo = __builtin_amdgcn_cvt_pk_f32_fp8((int)dw[k], false);
                f32x2_t hi = __builtin_amdgcn_cvt_pk_f32_fp8((int)dw[k], true);
                int c0 = t * 16 + k * 4;
                atomicAdd(&ap[c0 + 0], lo.x * wt);
                atomicAdd(&ap[c0 + 1], lo.y * wt);
                atomicAdd(&ap[c0 + 2], hi.x * wt);
                atomicAdd(&ap[c0 + 3], hi.y * wt);
            }
            atomicAdd(&ap[64 + t], wt);                   // denominator per head
        }
    }
    __syncthreads();
    // epilogue: normalize + bias + ELU -> fp16, coalesced
    for (int idx = tid; idx < nn * 64; idx += 256) {
        int n = idx >> 6, c = idx & 63;
        float den = acc[n * AS1 + 64 + (c >> 4)];
        float v = acc[n * AS1 + c] / (den + 1e-16f) + b1[c];
        v = v > 0.f ? v : __expf(v) - 1.f;  // fast ELU
        h1bg[(long long)(nb0 + n) * 64 + c] = __float2half_rn(v);
    }
}

// ---- MFMA: h2 = h1b @ W2 (fp16 out) + layer-2 logits. 16 nodes/wave ----
__global__ __launch_bounds__(256) void k_mid(
    const __half* __restrict__ h1bg, const float* __restrict__ W2,
    const float* __restrict__ a2s, const float* __restrict__ a2d,
    __half* __restrict__ h2, float* __restrict__ al2s, float* __restrict__ al2d)
{
    __shared__ float W2l[64 * 16];
    int tid = threadIdx.x;
    for (int i = tid; i < 64 * 16; i += 256) W2l[i] = W2[i];
    __syncthreads();
    int wv = tid >> 6, lane = tid & 63;
    int m = lane & 15, q = lane >> 4;
    // B-frag: lane holds B[k = s*32 + q*8 + j][n = m]
    half8_t bf[2];
#pragma unroll
    for (int s = 0; s < 2; ++s) {
        half8_t b;
#pragma unroll
        for (int j = 0; j < 8; ++j)
            b[j] = (_Float16)W2l[(s * 32 + q * 8 + j) * 16 + m];
        bf[s] = b;
    }
    int node0 = blockIdx.x * 64 + wv * 16;
    half8_t av0 = {}, av1 = {};
    if (node0 + m < N_NODES) {
        const __half* ar = h1bg + (long long)(node0 + m) * 64;
        av0 = *(const half8_t*)(ar + q * 8);        // 16B coalesced
        av1 = *(const half8_t*)(ar + 32 + q * 8);
    }
    f32x4_t acc = {0, 0, 0, 0};
    acc = __builtin_amdgcn_mfma_f32_16x16x32_f16(av0, bf[0], acc, 0, 0, 0);
    acc = __builtin_amdgcn_mfma_f32_16x16x32_f16(av1, bf[1], acc, 0, 0, 0);
    float a2sm = a2s[m], a2dm = a2d[m];
    // C: col=m (h2 channel), row=q*4+r (node within tile)
#pragma unroll
    for (int r = 0; r < 4; ++r) {
        int nr = node0 + q * 4 + r;
        bool ok = nr < N_NODES;
        float v = acc[r];
        if (ok) h2[nr * 16 + m] = __float2half_rn(v);
        float ps = v * a2sm, pd = v * a2dm;
        ps += __shfl_xor(ps, 1); ps += __shfl_xor(ps, 2);
        ps += __shfl_xor(ps, 4); ps += __shfl_xor(ps, 8);
        pd += __shfl_xor(pd, 1); pd += __shfl_xor(pd, 2);
        pd += __shfl_xor(pd, 4); pd += __shfl_xor(pd, 8);
        if (ok && m == 0) { al2s[nr] = ps; al2d[nr] = pd; }
    }
}

// ---- layer 2 aggregate: edge-parallel, LDS atomic accumulators ----
__global__ __launch_bounds__(256) void k_agg2(
    const unsigned int* __restrict__ ebuf, const int* __restrict__ gcnt,
    const __half* __restrict__ h2,
    const float* __restrict__ al2s, const float* __restrict__ al2d,
    const float* __restrict__ b2, float* __restrict__ hout)
{
    __shared__ float acc[128 * AS2];    // 10.5 KB: [dl][0..15]=ch, [16]=den
    int tid = threadIdx.x;
    int b = blockIdx.x;
    int nb0 = b << FBK_SHIFT;
    int nn = min(128, N_NODES - nb0);
    int cnt = min(gcnt[b], BCAP_F);     // clamped (matches write guard)
    for (int i = tid; i < 128 * AS2; i += 256) acc[i] = 0.f;
    __syncthreads();

    for (int i = tid; i < cnt; i += 256) {
        unsigned int ev = ebuf[b * BCAP_F + i];           // coalesced
        int s  = (int)(ev & 0x1FFFF);
        int dl = (int)(ev >> 17);
        float e = al2s[s] + al2d[nb0 + dl];               // gathers, latency-hidden
        e = e > 0.f ? e : SLOPE * e;
        float w = __expf(e);
        float* ap = acc + dl * AS2;
        const uint4* hp = (const uint4*)(h2 + (long long)s * 16);
        uint4 ra = hp[0], rb = hp[1];                     // 16 fp16 = 32B
        unsigned int dw[8] = {ra.x, ra.y, ra.z, ra.w, rb.x, rb.y, rb.z, rb.w};
#pragma unroll
        for (int k = 0; k < 8; ++k) {
            __half2 hv = *(__half2*)&dw[k];
            atomicAdd(&ap[2 * k + 0], __low2float(hv) * w);
            atomicAdd(&ap[2 * k + 1], __high2float(hv) * w);
        }
        atomicAdd(&ap[16], w);                            // denominator
    }
    __syncthreads();
    // epilogue: normalize + bias + ELU -> f32 hout, coalesced
    for (int idx = tid; idx < nn * 16; idx += 256) {
        int n = idx >> 4, c = idx & 15;
        float den = acc[n * AS2 + 16];
        float v = acc[n * AS2 + c] / (den + 1e-16f) + b2[c];
        v = v > 0.f ? v : __expf(v) - 1.f;  // fast ELU
        hout[(long long)(nb0 + n) * 16 + c] = v;
    }
}

// ---- mean-pool per graph (binary-search node range) + classifier ----
__global__ __launch_bounds__(256) void k_pool(
    const float* __restrict__ hout, const int* __restrict__ batch,
    const float* __restrict__ Wc, const float* __restrict__ bc, float* __restrict__ out)
{
    __shared__ float red[16][17];
    __shared__ int bnd[2];
    int g = blockIdx.x;
    int t = threadIdx.x, c = t & 15, slot = t >> 4;
    if (t < 2) {
        int key = g + t;                // lower_bound(batch, g) and (g+1)
        int lo = 0, hi = N_NODES;
        while (lo < hi) { int mid = (lo + hi) >> 1; if (batch[mid] < key) lo = mid + 1; else hi = mid; }
        bnd[t] = lo;
    }
    __syncthreads();
    int s = bnd[0], e = bnd[1];
    float sum = 0.f;
    for (int n = s + slot; n < e; n += 16)
        sum += hout[n * 16 + c];        // fully coalesced (1 KB / iter / block)
    red[slot][c] = sum;
    __syncthreads();
    if (t < 16) {
        float tot = 0.f;
#pragma unroll
        for (int k = 0; k < 16; ++k) tot += red[k][t];
        float cnt = fmaxf((float)(e - s), 1.0f);
        float pc = (tot / cnt) * Wc[t];
        pc += __shfl_xor(pc, 1); pc += __shfl_xor(pc, 2);
        pc += __shfl_xor(pc, 4); pc += __shfl_xor(pc, 8);
        if (t == 0) out[g] = pc + bc[0];
    }
}

extern "C" void kernel_launch(void* const* d_in, const int* in_sizes, int n_in,
                              void* d_out, int out_size, void* d_ws, size_t ws_size,
                              hipStream_t stream)
{
    const float* x    = (const float*)d_in[0];
    const int*   ei   = (const int*)d_in[1];
    const int*   batc = (const int*)d_in[2];
    const float* W1   = (const float*)d_in[3];
    const float* a1s  = (const float*)d_in[4];
    const float* a1d  = (const float*)d_in[5];
    const float* b1   = (const float*)d_in[6];
    const float* W2   = (const float*)d_in[7];
    const float* a2s  = (const float*)d_in[8];
    const float* a2d  = (const float*)d_in[9];
    const float* b2   = (const float*)d_in[10];
    const float* Wc   = (const float*)d_in[11];
    const float* bc   = (const float*)d_in[12];
    float* out = (float*)d_out;

    // ---- workspace carve, 16B-aligned chunks. Zero gcnt only, one memset. ----
    char* ws = (char*)d_ws;
    size_t off = 0;
    auto carveB = [&](size_t bytes) {
        void* p = ws + off;
        off += ((bytes + 15) & ~(size_t)15);
        return p;
    };
    auto carve = [&](size_t elems) { return carveB(elems * 4); };
    int*   gcnt   = (int*)  carve(NB_F);               // zeroed (bucket cursors)
    size_t zero_bytes = off;
    unsigned int* ebuf = (unsigned int*)carve((size_t)NB_F * BCAP_F);
    __hip_fp8_e4m3* h1 = (__hip_fp8_e4m3*)carveB((size_t)N_NODES * 64);
    float* al1s   = (float*)carve((size_t)N_NODES * 4);
    float* al1d   = (float*)carve((size_t)N_NODES * 4);
    __half* h1bg  = (__half*)carveB((size_t)N_NODES * 64 * 2);
    __half* h2    = (__half*)carveB((size_t)N_NODES * 16 * 2);
    float* al2s   = (float*)carve(N_NODES);
    float* al2d   = (float*)carve(N_NODES);
    float* hout   = (float*)carve((size_t)N_NODES * 16);

    hipMemsetAsync(d_ws, 0, zero_bytes, stream);

    k_prepA<<<NBLK_A + H1B4, 1024, 0, stream>>>(x, W1, a1s, a1d, ei, gcnt, ebuf, h1, al1s, al1d);
    k_agg1 <<<NB_F, 256, 0, stream>>>(ebuf, gcnt, h1, al1s, al1d, b1, h1bg);
    k_mid  <<<(N_NODES + 63) / 64, 256, 0, stream>>>(h1bg, W2, a2s, a2d, h2, al2s, al2d);
    k_agg2 <<<NB_F, 256, 0, stream>>>(ebuf, gcnt, h2, al2s, al2d, b2, hout);
    k_pool <<<NG, 256, 0, stream>>>(hout, batc, Wc, bc, out);
}

// Round 6
// 368.408 us; speedup vs baseline: 3.0213x; 3.0213x over previous
//
#include <hip/hip_runtime.h>
#include <hip/hip_fp16.h>
#include <hip/hip_fp8.h>

#define N_NODES 100000
#define N_EDGES 1600000
#define ET      (N_EDGES + N_NODES)   // 1,700,000
#define NG      512
#define SLOPE   0.2f

#define CHUNK_A 8192
#define NBLK_A ((ET + CHUNK_A - 1) / CHUNK_A)   // 208 edge-chunk blocks
#define H1B4   ((N_NODES + 1023) / 1024)        // 98 mfma blocks (1024 nodes each)
#define NBLK_S ((N_NODES + 1023) / 1024)        // 98 scan blocks

typedef _Float16 half8_t __attribute__((ext_vector_type(8)));
typedef float    f32x4_t __attribute__((ext_vector_type(4)));

// ---- fused: [deg role] degree histogram (native int atomics)
//      [prep role] MFMA h1 = x@W1 (fp8 out) + layer-1 logits ----
__global__ __launch_bounds__(1024) void k_prep(
    const float* __restrict__ x, const float* __restrict__ W1,
    const float* __restrict__ a1s, const float* __restrict__ a1d,
    const int* __restrict__ ei,
    int* __restrict__ deg,
    __hip_fp8_e4m3* __restrict__ h1, float* __restrict__ al1s, float* __restrict__ al1d)
{
    __shared__ float Wl[64 * 64];
    __shared__ float asf[64], adf[64];
    int tid = threadIdx.x;

    if (blockIdx.x < NBLK_A) {
        // ---------------- deg role: histogram 8K-edge chunk ----------------
        int base = blockIdx.x * CHUNK_A;
        int m = min(CHUNK_A, ET - base);
        for (int i = tid; i < m; i += 1024) {
            int eid = base + i;
            int d = (eid < N_EDGES) ? ei[N_EDGES + eid] : (eid - N_EDGES);
            atomicAdd(&deg[d], 1);              // native int32 atomic
        }
        return;
    }

    // ---------------- prep role: 16 waves x 16 nodes x 4 iters = 1024 nodes ----------------
    for (int i = tid; i < 64 * 64; i += 1024) Wl[i] = W1[i];
    if (tid < 64) { asf[tid] = a1s[tid]; adf[tid] = a1d[tid]; }
    __syncthreads();

    int wv = tid >> 6, lane = tid & 63;
    int m = lane & 15, q = lane >> 4;

    half8_t bf[4][2];
#pragma unroll
    for (int t = 0; t < 4; ++t)
#pragma unroll
        for (int s = 0; s < 2; ++s) {
            half8_t b;
#pragma unroll
            for (int j = 0; j < 8; ++j)
                b[j] = (_Float16)Wl[(s * 32 + q * 8 + j) * 64 + t * 16 + m];
            bf[t][s] = b;
        }

    int nodebase = (blockIdx.x - NBLK_A) * 1024 + wv * 64;
    for (int it = 0; it < 4; ++it) {
        int node0 = nodebase + it * 16;
        int node = node0 + m;
        half8_t av0 = {}, av1 = {};
        if (node < N_NODES) {
            const float4* xr = (const float4*)(x + (long long)node * 64);
            float4 p0 = xr[q * 2], p1 = xr[q * 2 + 1];
            float4 p2 = xr[q * 2 + 8], p3 = xr[q * 2 + 9];
            av0[0] = (_Float16)p0.x; av0[1] = (_Float16)p0.y;
            av0[2] = (_Float16)p0.z; av0[3] = (_Float16)p0.w;
            av0[4] = (_Float16)p1.x; av0[5] = (_Float16)p1.y;
            av0[6] = (_Float16)p1.z; av0[7] = (_Float16)p1.w;
            av1[0] = (_Float16)p2.x; av1[1] = (_Float16)p2.y;
            av1[2] = (_Float16)p2.z; av1[3] = (_Float16)p2.w;
            av1[4] = (_Float16)p3.x; av1[5] = (_Float16)p3.y;
            av1[6] = (_Float16)p3.z; av1[7] = (_Float16)p3.w;
        }
        f32x4_t acc[4] = {{0,0,0,0},{0,0,0,0},{0,0,0,0},{0,0,0,0}};
#pragma unroll
        for (int t = 0; t < 4; ++t) {
            acc[t] = __builtin_amdgcn_mfma_f32_16x16x32_f16(av0, bf[t][0], acc[t], 0, 0, 0);
            acc[t] = __builtin_amdgcn_mfma_f32_16x16x32_f16(av1, bf[t][1], acc[t], 0, 0, 0);
        }
#pragma unroll
        for (int r = 0; r < 4; ++r) {
            int nr = node0 + q * 4 + r;
            bool ok = nr < N_NODES;
#pragma unroll
            for (int t = 0; t < 4; ++t) {
                float v = acc[t][r];
                if (ok) h1[(long long)nr * 64 + t * 16 + m] = __hip_fp8_e4m3(v);
                float ps = v * asf[t * 16 + m];
                float pd = v * adf[t * 16 + m];
                ps += __shfl_xor(ps, 1); ps += __shfl_xor(ps, 2);
                ps += __shfl_xor(ps, 4); ps += __shfl_xor(ps, 8);
                pd += __shfl_xor(pd, 1); pd += __shfl_xor(pd, 2);
                pd += __shfl_xor(pd, 4); pd += __shfl_xor(pd, 8);
                if (ok && m == t) { al1s[nr * 4 + t] = ps; al1d[nr * 4 + t] = pd; }
            }
        }
    }
}

// ---- scan stage 1: per-1024-block exclusive scan of deg ----
__global__ __launch_bounds__(1024) void k_scanA(
    const int* __restrict__ deg, int* __restrict__ offs, int* __restrict__ bsum)
{
    __shared__ int tmp[1024];
    int tid = threadIdx.x;
    int gid = blockIdx.x * 1024 + tid;
    int v = (gid < N_NODES) ? deg[gid] : 0;
    tmp[tid] = v;
    __syncthreads();
    for (int off = 1; off < 1024; off <<= 1) {
        int t = (tid >= off) ? tmp[tid - off] : 0;
        __syncthreads();
        tmp[tid] += t;
        __syncthreads();
    }
    if (gid < N_NODES) offs[gid] = tmp[tid] - v;   // block-local exclusive
    if (tid == 1023) bsum[blockIdx.x] = tmp[tid];  // block total
}

// ---- scan stage 2: exclusive scan of 98 block sums (1 block) ----
__global__ __launch_bounds__(128) void k_scanB2(
    const int* __restrict__ bsum, int* __restrict__ bpre)
{
    __shared__ int tmp[128];
    int tid = threadIdx.x;
    int v = (tid < NBLK_S) ? bsum[tid] : 0;
    tmp[tid] = v;
    __syncthreads();
    for (int off = 1; off < 128; off <<= 1) {
        int t = (tid >= off) ? tmp[tid - off] : 0;
        __syncthreads();
        tmp[tid] += t;
        __syncthreads();
    }
    if (tid < NBLK_S) bpre[tid] = tmp[tid] - v;
}

// ---- scan fixup: finalize offs, init scatter cursor ----
__global__ __launch_bounds__(1024) void k_fix(
    int* __restrict__ offs, int* __restrict__ cur, const int* __restrict__ bpre)
{
    int gid = blockIdx.x * 1024 + threadIdx.x;
    if (gid < N_NODES) {
        int o = offs[gid] + bpre[blockIdx.x];
        offs[gid] = o;
        cur[gid] = o;
    }
}

// ---- scatter: direct CSR build (native int atomics, positions provably in range) ----
__global__ __launch_bounds__(1024) void k_scatter(
    const int* __restrict__ ei, int* __restrict__ cur, int* __restrict__ csr)
{
    int base = blockIdx.x * CHUNK_A;
    int m = min(CHUNK_A, ET - base);
    for (int i = threadIdx.x; i < m; i += 1024) {
        int eid = base + i;
        int s, d;
        if (eid < N_EDGES) { s = ei[eid]; d = ei[N_EDGES + eid]; }
        else               { s = eid - N_EDGES; d = s; }
        int pos = atomicAdd(&cur[d], 1);
        csr[pos] = s;
    }
}

// ---- layer 1 aggregate: 4 edges/iter x 16 lanes/edge (proven 50.6us form) ----
__global__ __launch_bounds__(256) void k_agg1(
    const int* __restrict__ offs, const int* __restrict__ deg, const int* __restrict__ csr,
    const __hip_fp8_e4m3* __restrict__ h1, const float* __restrict__ al1s, const float* __restrict__ al1d,
    const float* __restrict__ b1, __half* __restrict__ h1bg)
{
    __shared__ int   sarr[4][64];       // s*64 (pre-scaled byte row offset)
    __shared__ float warr[4][4 * 72];   // [wave][head*72 + j]: conflict-free
    __shared__ __align__(16) float h1b[4][64];
    int tid = threadIdx.x;
    int wv = tid >> 6, lane = tid & 63;
    int eslot = lane >> 4;              // which of 4 edges per iteration
    int cq = lane & 15;                 // channel quad: channels 4cq..4cq+3
    int h = cq >> 2;                    // head of this channel quad
    int cq4 = cq * 4;
    int node = blockIdx.x * 4 + wv;
    int st = offs[node], dg = deg[node];
    const float4 ald4 = *(const float4*)(al1d + node * 4);
    float b1l = b1[lane];               // coalesced, L1-hot
    const char* __restrict__ h1c = (const char*)h1;

    float a0 = 0.f, a1 = 0.f, a2 = 0.f, a3 = 0.f, den = 0.f;
    for (int base = 0; base < dg; base += 64) {
        int m = min(64, dg - base);
        int s = 0;
        float w0 = 0.f, w1 = 0.f, w2 = 0.f, w3 = 0.f;
        if (lane < m) {
            s = csr[st + base + lane];              // coalesced
            const float4 as4 = *(const float4*)(al1s + s * 4);  // 16B gather (L2-resident)
            float e0 = as4.x + ald4.x; e0 = e0 > 0.f ? e0 : SLOPE * e0;
            float e1 = as4.y + ald4.y; e1 = e1 > 0.f ? e1 : SLOPE * e1;
            float e2 = as4.z + ald4.z; e2 = e2 > 0.f ? e2 : SLOPE * e2;
            float e3 = as4.w + ald4.w; e3 = e3 > 0.f ? e3 : SLOPE * e3;
            w0 = __expf(e0); w1 = __expf(e1); w2 = __expf(e2); w3 = __expf(e3);
        }
        sarr[wv][lane] = s << 6;                    // pad lanes: s=0, w=0
        warr[wv][0 * 72 + lane] = w0;
        warr[wv][1 * 72 + lane] = w1;
        warr[wv][2 * 72 + lane] = w2;
        warr[wv][3 * 72 + lane] = w3;
        // intra-wave LDS dependency only — no barrier (trip counts diverge per wave)
        int m4 = (m + 3) & ~3;
#pragma unroll 4
        for (int j0 = 0; j0 < m4; j0 += 4) {
            int j = j0 + eslot;
            int off = sarr[wv][j] + cq4;            // 4-addr broadcast + add
            float wgt = warr[wv][h * 72 + j];       // 16 distinct banks, 4-lane bcast
            unsigned int pk = *(const unsigned int*)(h1c + off);  // 64B/edge
            a0 = fmaf(wgt, __builtin_amdgcn_cvt_f32_fp8(pk, 0), a0);
            a1 = fmaf(wgt, __builtin_amdgcn_cvt_f32_fp8(pk, 1), a1);
            a2 = fmaf(wgt, __builtin_amdgcn_cvt_f32_fp8(pk, 2), a2);
            a3 = fmaf(wgt, __builtin_amdgcn_cvt_f32_fp8(pk, 3), a3);
            den += wgt;
        }
    }
    // reduce over the 4 edge-slots; den[lane] = full denom for head (lane&15)>>2
    a0 += __shfl_xor(a0, 16); a0 += __shfl_xor(a0, 32);
    a1 += __shfl_xor(a1, 16); a1 += __shfl_xor(a1, 32);
    a2 += __shfl_xor(a2, 16); a2 += __shfl_xor(a2, 32);
    a3 += __shfl_xor(a3, 16); a3 += __shfl_xor(a3, 32);
    den += __shfl_xor(den, 16); den += __shfl_xor(den, 32);
    if (lane < 16)
        *(float4*)&h1b[wv][cq4] = make_float4(a0, a1, a2, a3);
    // channel `lane` needs head lane>>4's denominator: lane 4h holds head h's den
    float denc = __shfl(den, (lane >> 4) << 2);
    // intra-wave LDS, no barrier
    float v = h1b[wv][lane] / (denc + 1e-16f) + b1l;
    v = v > 0.f ? v : __expf(v) - 1.f;  // fast ELU
    h1bg[(long long)node * 64 + lane] = __float2half_rn(v);  // coalesced 128B
}

// ---- MFMA: h2 = h1b @ W2 (fp16 out) + layer-2 logits. 16 nodes/wave ----
__global__ __launch_bounds__(256) void k_mid(
    const __half* __restrict__ h1bg, const float* __restrict__ W2,
    const float* __restrict__ a2s, const float* __restrict__ a2d,
    __half* __restrict__ h2, float* __restrict__ al2s, float* __restrict__ al2d)
{
    __shared__ float W2l[64 * 16];
    int tid = threadIdx.x;
    for (int i = tid; i < 64 * 16; i += 256) W2l[i] = W2[i];
    __syncthreads();
    int wv = tid >> 6, lane = tid & 63;
    int m = lane & 15, q = lane >> 4;
    // B-frag: lane holds B[k = s*32 + q*8 + j][n = m]
    half8_t bf[2];
#pragma unroll
    for (int s = 0; s < 2; ++s) {
        half8_t b;
#pragma unroll
        for (int j = 0; j < 8; ++j)
            b[j] = (_Float16)W2l[(s * 32 + q * 8 + j) * 16 + m];
        bf[s] = b;
    }
    int node0 = blockIdx.x * 64 + wv * 16;
    half8_t av0 = {}, av1 = {};
    if (node0 + m < N_NODES) {
        const __half* ar = h1bg + (long long)(node0 + m) * 64;
        av0 = *(const half8_t*)(ar + q * 8);        // 16B coalesced
        av1 = *(const half8_t*)(ar + 32 + q * 8);
    }
    f32x4_t acc = {0, 0, 0, 0};
    acc = __builtin_amdgcn_mfma_f32_16x16x32_f16(av0, bf[0], acc, 0, 0, 0);
    acc = __builtin_amdgcn_mfma_f32_16x16x32_f16(av1, bf[1], acc, 0, 0, 0);
    float a2sm = a2s[m], a2dm = a2d[m];
    // C: col=m (h2 channel), row=q*4+r (node within tile)
#pragma unroll
    for (int r = 0; r < 4; ++r) {
        int nr = node0 + q * 4 + r;
        bool ok = nr < N_NODES;
        float v = acc[r];
        if (ok) h2[nr * 16 + m] = __float2half_rn(v);
        float ps = v * a2sm, pd = v * a2dm;
        ps += __shfl_xor(ps, 1); ps += __shfl_xor(ps, 2);
        ps += __shfl_xor(ps, 4); ps += __shfl_xor(ps, 8);
        pd += __shfl_xor(pd, 1); pd += __shfl_xor(pd, 2);
        pd += __shfl_xor(pd, 4); pd += __shfl_xor(pd, 8);
        if (ok && m == 0) { al2s[nr] = ps; al2d[nr] = pd; }
    }
}

// ---- layer 2 aggregate: 8 edges/iter, fp16 h2 (3.2MB, L2-resident), hout write ----
__global__ __launch_bounds__(256) void k_agg2(
    const int* __restrict__ offs, const int* __restrict__ deg, const int* __restrict__ csr,
    const __half* __restrict__ h2, const float* __restrict__ al2s, const float* __restrict__ al2d,
    const float* __restrict__ b2, float* __restrict__ hout)
{
    __shared__ int   sarr[4][64];
    __shared__ float warr[4][64];
    int tid = threadIdx.x;
    int wv = tid >> 6, lane = tid & 63;
    int ec = lane >> 3, cc = lane & 7;  // 8 edges x 8 channel-pairs
    int node = blockIdx.x * 4 + wv;
    int st = offs[node], dg = deg[node];
    float ald = al2d[node];
    const __half2* __restrict__ h2v = (const __half2*)h2;

    float a0 = 0.f, a1 = 0.f, den = 0.f;
    for (int base = 0; base < dg; base += 64) {
        int m = min(64, dg - base);
        int s = 0; float wl = 0.f;
        if (lane < m) {
            s = csr[st + base + lane];              // coalesced
            float e = al2s[s] + ald;                // 64 independent gathers (L2-resident)
            e = e > 0.f ? e : SLOPE * e;
            wl = __expf(e);
        }
        sarr[wv][lane] = s;                         // pad: s=0, w=0
        warr[wv][lane] = wl;
        // intra-wave LDS dependency only — no barrier
        int m8 = (m + 7) & ~7;
#pragma unroll 2
        for (int j0 = 0; j0 < m8; j0 += 8) {
            int j = j0 + ec;
            int s2i = sarr[wv][j];                  // 8-addr broadcast
            float wgt = warr[wv][j];
            __half2 hv = h2v[s2i * 8 + cc];         // 32B row, 8 rows in flight
            a0 = fmaf(__low2float(hv), wgt, a0);
            a1 = fmaf(__high2float(hv), wgt, a1);
            den += wgt;                             // each edge counted once per cc-lane
        }
    }
    // xor 8/16/32 reduces across the 8 edge-slots: completes a0,a1 AND den
    a0 += __shfl_xor(a0, 8);  a1 += __shfl_xor(a1, 8);  den += __shfl_xor(den, 8);
    a0 += __shfl_xor(a0, 16); a1 += __shfl_xor(a1, 16); den += __shfl_xor(den, 16);
    a0 += __shfl_xor(a0, 32); a1 += __shfl_xor(a1, 32); den += __shfl_xor(den, 32);
    if (lane < 8) {
        float inv = 1.f / (den + 1e-16f);
        float v0 = a0 * inv + b2[2 * cc];
        float v1 = a1 * inv + b2[2 * cc + 1];
        v0 = v0 > 0.f ? v0 : __expf(v0) - 1.f;  // fast ELU
        v1 = v1 > 0.f ? v1 : __expf(v1) - 1.f;
        ((float2*)hout)[node * 8 + cc] = make_float2(v0, v1);  // coalesced
    }
}

// ---- mean-pool per graph (binary-search node range) + classifier ----
__global__ __launch_bounds__(256) void k_pool(
    const float* __restrict__ hout, const int* __restrict__ batch,
    const float* __restrict__ Wc, const float* __restrict__ bc, float* __restrict__ out)
{
    __shared__ float red[16][17];
    __shared__ int bnd[2];
    int g = blockIdx.x;
    int t = threadIdx.x, c = t & 15, slot = t >> 4;
    if (t < 2) {
        int key = g + t;                // lower_bound(batch, g) and (g+1)
        int lo = 0, hi = N_NODES;
        while (lo < hi) { int mid = (lo + hi) >> 1; if (batch[mid] < key) lo = mid + 1; else hi = mid; }
        bnd[t] = lo;
    }
    __syncthreads();
    int s = bnd[0], e = bnd[1];
    float sum = 0.f;
    for (int n = s + slot; n < e; n += 16)
        sum += hout[n * 16 + c];        // fully coalesced (1 KB / iter / block)
    red[slot][c] = sum;
    __syncthreads();
    if (t < 16) {
        float tot = 0.f;
#pragma unroll
        for (int k = 0; k < 16; ++k) tot += red[k][t];
        float cnt = fmaxf((float)(e - s), 1.0f);
        float pc = (tot / cnt) * Wc[t];
        pc += __shfl_xor(pc, 1); pc += __shfl_xor(pc, 2);
        pc += __shfl_xor(pc, 4); pc += __shfl_xor(pc, 8);
        if (t == 0) out[g] = pc + bc[0];
    }
}

extern "C" void kernel_launch(void* const* d_in, const int* in_sizes, int n_in,
                              void* d_out, int out_size, void* d_ws, size_t ws_size,
                              hipStream_t stream)
{
    const float* x    = (const float*)d_in[0];
    const int*   ei   = (const int*)d_in[1];
    const int*   batc = (const int*)d_in[2];
    const float* W1   = (const float*)d_in[3];
    const float* a1s  = (const float*)d_in[4];
    const float* a1d  = (const float*)d_in[5];
    const float* b1   = (const float*)d_in[6];
    const float* W2   = (const float*)d_in[7];
    const float* a2s  = (const float*)d_in[8];
    const float* a2d  = (const float*)d_in[9];
    const float* b2   = (const float*)d_in[10];
    const float* Wc   = (const float*)d_in[11];
    const float* bc   = (const float*)d_in[12];
    float* out = (float*)d_out;

    // ---- workspace carve, 16B-aligned chunks. Zero deg only, one memset. ----
    char* ws = (char*)d_ws;
    size_t off = 0;
    auto carveB = [&](size_t bytes) {
        void* p = ws + off;
        off += ((bytes + 15) & ~(size_t)15);
        return p;
    };
    auto carve = [&](size_t elems) { return carveB(elems * 4); };
    int*   deg    = (int*)  carve(N_NODES);            // zeroed (histogram)
    size_t zero_bytes = off;
    int*   offs   = (int*)  carve(N_NODES);
    int*   cur    = (int*)  carve(N_NODES);
    int*   bsum   = (int*)  carve(NBLK_S);
    int*   bpre   = (int*)  carve(NBLK_S);
    int*   csr    = (int*)  carve(ET);
    __hip_fp8_e4m3* h1 = (__hip_fp8_e4m3*)carveB((size_t)N_NODES * 64);
    float* al1s   = (float*)carve((size_t)N_NODES * 4);
    float* al1d   = (float*)carve((size_t)N_NODES * 4);
    __half* h1bg  = (__half*)carveB((size_t)N_NODES * 64 * 2);
    __half* h2    = (__half*)carveB((size_t)N_NODES * 16 * 2);
    float* al2s   = (float*)carve(N_NODES);
    float* al2d   = (float*)carve(N_NODES);
    float* hout   = (float*)carve((size_t)N_NODES * 16);

    hipMemsetAsync(d_ws, 0, zero_bytes, stream);

    k_prep   <<<NBLK_A + H1B4, 1024, 0, stream>>>(x, W1, a1s, a1d, ei, deg, h1, al1s, al1d);
    k_scanA  <<<NBLK_S, 1024, 0, stream>>>(deg, offs, bsum);
    k_scanB2 <<<1, 128, 0, stream>>>(bsum, bpre);
    k_fix    <<<NBLK_S, 1024, 0, stream>>>(offs, cur, bpre);
    k_scatter<<<NBLK_A, 1024, 0, stream>>>(ei, cur, csr);
    k_agg1   <<<N_NODES / 4, 256, 0, stream>>>(offs, deg, csr, h1, al1s, al1d, b1, h1bg);
    k_mid    <<<(N_NODES + 63) / 64, 256, 0, stream>>>(h1bg, W2, a2s, a2d, h2, al2s, al2d);
    k_agg2   <<<N_NODES / 4, 256, 0, stream>>>(offs, deg, csr, h2, al2s, al2d, b2, hout);
    k_pool   <<<NG, 256, 0, stream>>>(hout, batc, Wc, bc, out);
}

// Round 7
// 308.489 us; speedup vs baseline: 3.6081x; 1.1942x over previous
//
#include <hip/hip_runtime.h>
#include <hip/hip_fp16.h>
#include <hip/hip_fp8.h>

#define N_NODES 100000
#define N_EDGES 1600000
#define ET      (N_EDGES + N_NODES)   // 1,700,000
#define NG      512
#define SLOPE   0.2f

#define BKT_SHIFT 9                         // 512 nodes per bucket
#define NB_B   ((N_NODES + 511) / 512)      // 196 buckets
#define BCAP   10240                        // fixed bucket capacity: mean 8673, +16 sigma
#define CHUNK_A 8192
#define NBLK_A ((ET + CHUNK_A - 1) / CHUNK_A)   // 208
#define H1B4   ((N_NODES + 1023) / 1024)        // 98 mfma blocks (1024 nodes each)

typedef _Float16 half8_t __attribute__((ext_vector_type(8)));
typedef float    f32x4_t __attribute__((ext_vector_type(4)));
typedef float    f32x2_t __attribute__((ext_vector_type(2)));

// ---- fused: [passA role] LDS counting sort into fixed-capacity 512-node buckets
//      [prep role]  MFMA h1 = x@W1 (fp8 out) + layer-1 logits  (round-2 proven) ----
__global__ __launch_bounds__(1024) void k_prepA(
    const float* __restrict__ x, const float* __restrict__ W1,
    const float* __restrict__ a1s, const float* __restrict__ a1d,
    const int* __restrict__ ei,
    int* __restrict__ gcnt, unsigned int* __restrict__ ebuf,
    __hip_fp8_e4m3* __restrict__ h1, float* __restrict__ al1s, float* __restrict__ al1d)
{
    __shared__ union U {
        struct { float Wl[64 * 64]; float asf[64]; float adf[64]; } p;       // 16.9 KB
        struct { unsigned int stage[CHUNK_A]; unsigned char sbin[CHUNK_A];
                 int hist[NB_B]; int binst[NB_B]; int resv[NB_B]; int cur[NB_B];
                 int tmp[1024]; } a;                                         // 48.2 KB
    } u;
    int tid = threadIdx.x;

    if (blockIdx.x < NBLK_A) {
        // ---------------- passA role: sort 8K-edge chunk by dst-bucket ----------------
        int base = blockIdx.x * CHUNK_A;
        int m = min(CHUNK_A, ET - base);
        for (int i = tid; i < NB_B; i += 1024) u.a.hist[i] = 0;
        __syncthreads();
        for (int i = tid; i < m; i += 1024) {
            int eid = base + i;
            int d = (eid < N_EDGES) ? ei[N_EDGES + eid] : (eid - N_EDGES);
            atomicAdd(&u.a.hist[d >> BKT_SHIFT], 1);
        }
        __syncthreads();
        int v = (tid < NB_B) ? u.a.hist[tid] : 0;
        u.a.tmp[tid] = v;
        __syncthreads();
        for (int off = 1; off < 1024; off <<= 1) {
            int t = (tid >= off) ? u.a.tmp[tid - off] : 0;
            __syncthreads();
            u.a.tmp[tid] += t;
            __syncthreads();
        }
        if (tid < NB_B) {
            int e = u.a.tmp[tid] - v;
            u.a.binst[tid] = e;
            u.a.cur[tid] = e;
            u.a.resv[tid] = v ? atomicAdd(&gcnt[tid], v) : 0;  // offset within fixed bucket
        }
        __syncthreads();
        for (int i = tid; i < m; i += 1024) {
            int eid = base + i;
            int s, d;
            if (eid < N_EDGES) { s = ei[eid]; d = ei[N_EDGES + eid]; }
            else               { s = eid - N_EDGES; d = s; }
            int b = d >> BKT_SHIFT;
            int pos = atomicAdd(&u.a.cur[b], 1);
            u.a.stage[pos] = ((unsigned int)(d & 511) << 17) | (unsigned int)s;
            u.a.sbin[pos] = (unsigned char)b;
        }
        __syncthreads();
        for (int i = tid; i < m; i += 1024) {
            int b = u.a.sbin[i];
            int dst = u.a.resv[b] + (i - u.a.binst[b]);
            if (dst < BCAP)                       // OOB guard (stat. unreachable)
                ebuf[b * BCAP + dst] = u.a.stage[i];
        }
        return;
    }

    // ---------------- prep role: 16 waves x 16 nodes x 4 iters = 1024 nodes ----------------
    for (int i = tid; i < 64 * 64; i += 1024) u.p.Wl[i] = W1[i];
    if (tid < 64) { u.p.asf[tid] = a1s[tid]; u.p.adf[tid] = a1d[tid]; }
    __syncthreads();

    int wv = tid >> 6, lane = tid & 63;
    int m = lane & 15, q = lane >> 4;

    half8_t bf[4][2];
#pragma unroll
    for (int t = 0; t < 4; ++t)
#pragma unroll
        for (int s = 0; s < 2; ++s) {
            half8_t b;
#pragma unroll
            for (int j = 0; j < 8; ++j)
                b[j] = (_Float16)u.p.Wl[(s * 32 + q * 8 + j) * 64 + t * 16 + m];
            bf[t][s] = b;
        }

    int nodebase = (blockIdx.x - NBLK_A) * 1024 + wv * 64;
    for (int it = 0; it < 4; ++it) {
        int node0 = nodebase + it * 16;
        int node = node0 + m;
        half8_t av0 = {}, av1 = {};
        if (node < N_NODES) {
            const float4* xr = (const float4*)(x + (long long)node * 64);
            float4 p0 = xr[q * 2], p1 = xr[q * 2 + 1];
            float4 p2 = xr[q * 2 + 8], p3 = xr[q * 2 + 9];
            av0[0] = (_Float16)p0.x; av0[1] = (_Float16)p0.y;
            av0[2] = (_Float16)p0.z; av0[3] = (_Float16)p0.w;
            av0[4] = (_Float16)p1.x; av0[5] = (_Float16)p1.y;
            av0[6] = (_Float16)p1.z; av0[7] = (_Float16)p1.w;
            av1[0] = (_Float16)p2.x; av1[1] = (_Float16)p2.y;
            av1[2] = (_Float16)p2.z; av1[3] = (_Float16)p2.w;
            av1[4] = (_Float16)p3.x; av1[5] = (_Float16)p3.y;
            av1[6] = (_Float16)p3.z; av1[7] = (_Float16)p3.w;
        }
        f32x4_t acc[4] = {{0,0,0,0},{0,0,0,0},{0,0,0,0},{0,0,0,0}};
#pragma unroll
        for (int t = 0; t < 4; ++t) {
            acc[t] = __builtin_amdgcn_mfma_f32_16x16x32_f16(av0, bf[t][0], acc[t], 0, 0, 0);
            acc[t] = __builtin_amdgcn_mfma_f32_16x16x32_f16(av1, bf[t][1], acc[t], 0, 0, 0);
        }
#pragma unroll
        for (int r = 0; r < 4; ++r) {
            int nr = node0 + q * 4 + r;
            bool ok = nr < N_NODES;
#pragma unroll
            for (int t = 0; t < 4; ++t) {
                float v = acc[t][r];
                if (ok) h1[(long long)nr * 64 + t * 16 + m] = __hip_fp8_e4m3(v);
                float ps = v * u.p.asf[t * 16 + m];
                float pd = v * u.p.adf[t * 16 + m];
                ps += __shfl_xor(ps, 1); ps += __shfl_xor(ps, 2);
                ps += __shfl_xor(ps, 4); ps += __shfl_xor(ps, 8);
                pd += __shfl_xor(pd, 1); pd += __shfl_xor(pd, 2);
                pd += __shfl_xor(pd, 4); pd += __shfl_xor(pd, 8);
                if (ok && m == t) { al1s[nr * 4 + t] = ps; al1d[nr * 4 + t] = pd; }
            }
        }
    }
}

// ---- pass B: per-bucket node hist+scan + csr scatter (1024 threads, LDS atomics) ----
__global__ __launch_bounds__(1024) void k_passB(
    const unsigned int* __restrict__ ebuf, const int* __restrict__ gcnt,
    int* __restrict__ csr, int* __restrict__ offs, int* __restrict__ deg)
{
    __shared__ int ldeg[512];
    __shared__ int lofs[512];
    __shared__ int lcur[512];
    int tid = threadIdx.x;
    int b = blockIdx.x;
    int nb0 = b << BKT_SHIFT;
    int nn = min(512, N_NODES - nb0);
    int gbase = b * BCAP, cnt = min(gcnt[b], BCAP);
    if (tid < 512) ldeg[tid] = 0;
    __syncthreads();
    for (int i = tid; i < cnt; i += 1024)
        atomicAdd(&ldeg[ebuf[gbase + i] >> 17], 1);
    __syncthreads();
    int v = 0;
    if (tid < 512) { v = ldeg[tid]; lofs[tid] = v; }
    __syncthreads();
    for (int off = 1; off < 512; off <<= 1) {
        int t = (tid >= off && tid < 512) ? lofs[tid - off] : 0;
        __syncthreads();
        if (tid < 512) lofs[tid] += t;
        __syncthreads();
    }
    if (tid < 512) {
        int e = lofs[tid] - v;                  // exclusive
        lcur[tid] = e;
        if (tid < nn) { offs[nb0 + tid] = gbase + e; deg[nb0 + tid] = v; }
    }
    __syncthreads();
    for (int i = tid; i < cnt; i += 1024) {
        unsigned int ev = ebuf[gbase + i];
        int dl = ev >> 17, s = (int)(ev & 0x1FFFF);
        int p = atomicAdd(&lcur[dl], 1);
        csr[gbase + p] = s;
    }
}

// ---- layer 1 aggregate: 16 edges/iter x 4 lanes/edge x 16B/lane ----
// lane = (es<<2)|qd : es = edge slot (0..15), qd = head = channel quad-of-16 (0..3)
__global__ __launch_bounds__(256) void k_agg1(
    const int* __restrict__ offs, const int* __restrict__ deg, const int* __restrict__ csr,
    const __hip_fp8_e4m3* __restrict__ h1, const float* __restrict__ al1s, const float* __restrict__ al1d,
    const float* __restrict__ b1, __half* __restrict__ h1bg)
{
    __shared__ int   sarr[4][64];       // s*64 (pre-scaled byte row offset)
    __shared__ float warr[4][4 * 72];   // [wave][head*72 + j]: <=2-way (free)
    __shared__ __align__(16) float h1b[4][64];
    int tid = threadIdx.x;
    int wv = tid >> 6, lane = tid & 63;
    int es = lane >> 2;                 // edge slot
    int qd = lane & 3;                  // head / 16-channel quad
    int node = blockIdx.x * 4 + wv;
    int st = offs[node], dg = deg[node];
    const float4 ald4 = *(const float4*)(al1d + node * 4);
    float b1l = b1[lane];               // coalesced, L1-hot
    const char* __restrict__ h1c = (const char*)h1;

    f32x2_t acc[8] = {{0,0},{0,0},{0,0},{0,0},{0,0},{0,0},{0,0},{0,0}};
    float den = 0.f;
    for (int base = 0; base < dg; base += 64) {
        int m = min(64, dg - base);
        int s = 0;
        float w0 = 0.f, w1 = 0.f, w2 = 0.f, w3 = 0.f;
        if (lane < m) {
            s = csr[st + base + lane];              // coalesced
            const float4 as4 = *(const float4*)(al1s + s * 4);  // 16B gather (L2-resident)
            float e0 = as4.x + ald4.x; e0 = e0 > 0.f ? e0 : SLOPE * e0;
            float e1 = as4.y + ald4.y; e1 = e1 > 0.f ? e1 : SLOPE * e1;
            float e2 = as4.z + ald4.z; e2 = e2 > 0.f ? e2 : SLOPE * e2;
            float e3 = as4.w + ald4.w; e3 = e3 > 0.f ? e3 : SLOPE * e3;
            w0 = __expf(e0); w1 = __expf(e1); w2 = __expf(e2); w3 = __expf(e3);
        }
        sarr[wv][lane] = s << 6;                    // pad lanes: s=0, w=0
        warr[wv][0 * 72 + lane] = w0;
        warr[wv][1 * 72 + lane] = w1;
        warr[wv][2 * 72 + lane] = w2;
        warr[wv][3 * 72 + lane] = w3;
        // intra-wave LDS dependency only — no barrier (trip counts diverge per wave)
        int m16 = (m + 15) & ~15;
#pragma unroll 2
        for (int j0 = 0; j0 < m16; j0 += 16) {
            int j = j0 + es;
            int off = sarr[wv][j] + qd * 16;        // 4-lane broadcast + add
            float wgt = warr[wv][qd * 72 + j];      // banks qd*8+es: 2-way (free)
            uint4 r = *(const uint4*)(h1c + off);   // 16B: one head's 16 fp8
            f32x2_t wg2 = {wgt, wgt};
            unsigned int dw[4] = {r.x, r.y, r.z, r.w};
#pragma unroll
            for (int k = 0; k < 4; ++k) {
                acc[2 * k]     = __builtin_elementwise_fma(wg2,
                    __builtin_amdgcn_cvt_pk_f32_fp8((int)dw[k], false), acc[2 * k]);
                acc[2 * k + 1] = __builtin_elementwise_fma(wg2,
                    __builtin_amdgcn_cvt_pk_f32_fp8((int)dw[k], true),  acc[2 * k + 1]);
            }
            den += wgt;                             // head qd: once per (edge, head)
        }
    }
    // reduce across the 16 edge slots (xor 4..32 preserves qd)
#pragma unroll
    for (int x = 4; x <= 32; x <<= 1) {
#pragma unroll
        for (int k = 0; k < 8; ++k) {
            acc[k].x += __shfl_xor(acc[k].x, x);
            acc[k].y += __shfl_xor(acc[k].y, x);
        }
        den += __shfl_xor(den, x);
    }
    if (lane < 4) {                     // lane qd holds channels 16qd..16qd+15
        int c0 = lane * 16;
        *(float4*)&h1b[wv][c0 + 0]  = make_float4(acc[0].x, acc[0].y, acc[1].x, acc[1].y);
        *(float4*)&h1b[wv][c0 + 4]  = make_float4(acc[2].x, acc[2].y, acc[3].x, acc[3].y);
        *(float4*)&h1b[wv][c0 + 8]  = make_float4(acc[4].x, acc[4].y, acc[5].x, acc[5].y);
        *(float4*)&h1b[wv][c0 + 12] = make_float4(acc[6].x, acc[6].y, acc[7].x, acc[7].y);
    }
    float denc = __shfl(den, lane >> 4);            // head h's den lives on lane h
    // intra-wave LDS, no barrier
    float v = h1b[wv][lane] / (denc + 1e-16f) + b1l;
    v = v > 0.f ? v : __expf(v) - 1.f;  // fast ELU
    h1bg[(long long)node * 64 + lane] = __float2half_rn(v);  // coalesced 128B
}

// ---- MFMA: h2 = h1b @ W2 (fp16 out) + layer-2 logits. 16 nodes/wave ----
__global__ __launch_bounds__(256) void k_mid(
    const __half* __restrict__ h1bg, const float* __restrict__ W2,
    const float* __restrict__ a2s, const float* __restrict__ a2d,
    __half* __restrict__ h2, float* __restrict__ al2s, float* __restrict__ al2d)
{
    __shared__ float W2l[64 * 16];
    int tid = threadIdx.x;
    for (int i = tid; i < 64 * 16; i += 256) W2l[i] = W2[i];
    __syncthreads();
    int wv = tid >> 6, lane = tid & 63;
    int m = lane & 15, q = lane >> 4;
    // B-frag: lane holds B[k = s*32 + q*8 + j][n = m]
    half8_t bf[2];
#pragma unroll
    for (int s = 0; s < 2; ++s) {
        half8_t b;
#pragma unroll
        for (int j = 0; j < 8; ++j)
            b[j] = (_Float16)W2l[(s * 32 + q * 8 + j) * 16 + m];
        bf[s] = b;
    }
    int node0 = blockIdx.x * 64 + wv * 16;
    half8_t av0 = {}, av1 = {};
    if (node0 + m < N_NODES) {
        const __half* ar = h1bg + (long long)(node0 + m) * 64;
        av0 = *(const half8_t*)(ar + q * 8);        // 16B coalesced
        av1 = *(const half8_t*)(ar + 32 + q * 8);
    }
    f32x4_t acc = {0, 0, 0, 0};
    acc = __builtin_amdgcn_mfma_f32_16x16x32_f16(av0, bf[0], acc, 0, 0, 0);
    acc = __builtin_amdgcn_mfma_f32_16x16x32_f16(av1, bf[1], acc, 0, 0, 0);
    float a2sm = a2s[m], a2dm = a2d[m];
    // C: col=m (h2 channel), row=q*4+r (node within tile)
#pragma unroll
    for (int r = 0; r < 4; ++r) {
        int nr = node0 + q * 4 + r;
        bool ok = nr < N_NODES;
        float v = acc[r];
        if (ok) h2[nr * 16 + m] = __float2half_rn(v);
        float ps = v * a2sm, pd = v * a2dm;
        ps += __shfl_xor(ps, 1); ps += __shfl_xor(ps, 2);
        ps += __shfl_xor(ps, 4); ps += __shfl_xor(ps, 8);
        pd += __shfl_xor(pd, 1); pd += __shfl_xor(pd, 2);
        pd += __shfl_xor(pd, 4); pd += __shfl_xor(pd, 8);
        if (ok && m == 0) { al2s[nr] = ps; al2d[nr] = pd; }
    }
}

// ---- layer 2 aggregate: 32 edges/iter x 2 lanes/edge x 16B/lane ----
// lane = (es<<1)|hf : es = edge slot (0..31), hf = channel half (0..1)
__global__ __launch_bounds__(256) void k_agg2(
    const int* __restrict__ offs, const int* __restrict__ deg, const int* __restrict__ csr,
    const __half* __restrict__ h2, const float* __restrict__ al2s, const float* __restrict__ al2d,
    const float* __restrict__ b2, float* __restrict__ hout)
{
    __shared__ int   sarr[4][64];
    __shared__ float warr[4][64];
    __shared__ __align__(16) float h2b[4][16];
    int tid = threadIdx.x;
    int wv = tid >> 6, lane = tid & 63;
    int es = lane >> 1;                 // edge slot
    int hf = lane & 1;                  // channel half: 8hf..8hf+7
    int node = blockIdx.x * 4 + wv;
    int st = offs[node], dg = deg[node];
    float ald = al2d[node];
    const char* __restrict__ h2c = (const char*)h2;

    f32x2_t acc[4] = {{0,0},{0,0},{0,0},{0,0}};
    float den = 0.f;
    for (int base = 0; base < dg; base += 64) {
        int m = min(64, dg - base);
        int s = 0; float wl = 0.f;
        if (lane < m) {
            s = csr[st + base + lane];              // coalesced
            float e = al2s[s] + ald;                // 64 independent gathers (L2-resident)
            e = e > 0.f ? e : SLOPE * e;
            wl = __expf(e);
        }
        sarr[wv][lane] = s << 5;                    // 32B row byte offset; pad: s=0,w=0
        warr[wv][lane] = wl;
        // intra-wave LDS dependency only — no barrier
        int m32 = (m + 31) & ~31;
#pragma unroll 2
        for (int j0 = 0; j0 < m32; j0 += 32) {
            int j = j0 + es;
            int off = sarr[wv][j] + hf * 16;        // 2-lane broadcast + add
            float wgt = warr[wv][j];                // 32 distinct banks, 2-way
            uint4 r = *(const uint4*)(h2c + off);   // 16B: 8 fp16
            unsigned int dw[4] = {r.x, r.y, r.z, r.w};
#pragma unroll
            for (int k = 0; k < 4; ++k) {
                __half2 hv = *(__half2*)&dw[k];
                acc[k].x = fmaf(__low2float(hv),  wgt, acc[k].x);
                acc[k].y = fmaf(__high2float(hv), wgt, acc[k].y);
            }
            if (!hf) den += wgt;                    // count each edge once
        }
    }
    // reduce across the 32 edge slots (xor 2..32 preserves hf)
#pragma unroll
    for (int x = 2; x <= 32; x <<= 1) {
#pragma unroll
        for (int k = 0; k < 4; ++k) {
            acc[k].x += __shfl_xor(acc[k].x, x);
            acc[k].y += __shfl_xor(acc[k].y, x);
        }
        den += __shfl_xor(den, x);
    }
    den = __shfl(den, 0);               // full denom (accumulated on even lanes)
    if (lane < 2) {                     // lane hf holds channels 8hf..8hf+7
        int c0 = lane * 8;
        *(float4*)&h2b[wv][c0 + 0] = make_float4(acc[0].x, acc[0].y, acc[1].x, acc[1].y);
        *(float4*)&h2b[wv][c0 + 4] = make_float4(acc[2].x, acc[2].y, acc[3].x, acc[3].y);
    }
    // intra-wave LDS, no barrier
    if (lane < 8) {
        float inv = 1.f / (den + 1e-16f);
        float v0 = h2b[wv][2 * lane]     * inv + b2[2 * lane];
        float v1 = h2b[wv][2 * lane + 1] * inv + b2[2 * lane + 1];
        v0 = v0 > 0.f ? v0 : __expf(v0) - 1.f;  // fast ELU
        v1 = v1 > 0.f ? v1 : __expf(v1) - 1.f;
        ((float2*)hout)[node * 8 + lane] = make_float2(v0, v1);  // coalesced
    }
}

// ---- mean-pool per graph (binary-search node range) + classifier ----
__global__ __launch_bounds__(256) void k_pool(
    const float* __restrict__ hout, const int* __restrict__ batch,
    const float* __restrict__ Wc, const float* __restrict__ bc, float* __restrict__ out)
{
    __shared__ float red[16][17];
    __shared__ int bnd[2];
    int g = blockIdx.x;
    int t = threadIdx.x, c = t & 15, slot = t >> 4;
    if (t < 2) {
        int key = g + t;                // lower_bound(batch, g) and (g+1)
        int lo = 0, hi = N_NODES;
        while (lo < hi) { int mid = (lo + hi) >> 1; if (batch[mid] < key) lo = mid + 1; else hi = mid; }
        bnd[t] = lo;
    }
    __syncthreads();
    int s = bnd[0], e = bnd[1];
    float sum = 0.f;
    for (int n = s + slot; n < e; n += 16)
        sum += hout[n * 16 + c];        // fully coalesced (1 KB / iter / block)
    red[slot][c] = sum;
    __syncthreads();
    if (t < 16) {
        float tot = 0.f;
#pragma unroll
        for (int k = 0; k < 16; ++k) tot += red[k][t];
        float cnt = fmaxf((float)(e - s), 1.0f);
        float pc = (tot / cnt) * Wc[t];
        pc += __shfl_xor(pc, 1); pc += __shfl_xor(pc, 2);
        pc += __shfl_xor(pc, 4); pc += __shfl_xor(pc, 8);
        if (t == 0) out[g] = pc + bc[0];
    }
}

extern "C" void kernel_launch(void* const* d_in, const int* in_sizes, int n_in,
                              void* d_out, int out_size, void* d_ws, size_t ws_size,
                              hipStream_t stream)
{
    const float* x    = (const float*)d_in[0];
    const int*   ei   = (const int*)d_in[1];
    const int*   batc = (const int*)d_in[2];
    const float* W1   = (const float*)d_in[3];
    const float* a1s  = (const float*)d_in[4];
    const float* a1d  = (const float*)d_in[5];
    const float* b1   = (const float*)d_in[6];
    const float* W2   = (const float*)d_in[7];
    const float* a2s  = (const float*)d_in[8];
    const float* a2d  = (const float*)d_in[9];
    const float* b2   = (const float*)d_in[10];
    const float* Wc   = (const float*)d_in[11];
    const float* bc   = (const float*)d_in[12];
    float* out = (float*)d_out;

    // ---- workspace carve, 16B-aligned chunks. Zero gcnt only, one memset. ----
    char* ws = (char*)d_ws;
    size_t off = 0;
    auto carveB = [&](size_t bytes) {
        void* p = ws + off;
        off += ((bytes + 15) & ~(size_t)15);
        return p;
    };
    auto carve = [&](size_t elems) { return carveB(elems * 4); };
    int*   gcnt   = (int*)  carve(NB_B);               // zeroed (bucket cursors)
    size_t zero_bytes = off;
    unsigned int* ebuf = (unsigned int*)carve((size_t)NB_B * BCAP);
    int*   csr    = (int*)  carve((size_t)NB_B * BCAP);
    int*   offs   = (int*)  carve(N_NODES);
    int*   deg    = (int*)  carve(N_NODES);
    __hip_fp8_e4m3* h1 = (__hip_fp8_e4m3*)carveB((size_t)N_NODES * 64);
    float* al1s   = (float*)carve((size_t)N_NODES * 4);
    float* al1d   = (float*)carve((size_t)N_NODES * 4);
    __half* h1bg  = (__half*)carveB((size_t)N_NODES * 64 * 2);
    __half* h2    = (__half*)carveB((size_t)N_NODES * 16 * 2);
    float* al2s   = (float*)carve(N_NODES);
    float* al2d   = (float*)carve(N_NODES);
    float* hout   = (float*)carve((size_t)N_NODES * 16);

    hipMemsetAsync(d_ws, 0, zero_bytes, stream);

    k_prepA<<<NBLK_A + H1B4, 1024, 0, stream>>>(x, W1, a1s, a1d, ei, gcnt, ebuf, h1, al1s, al1d);
    k_passB<<<NB_B, 1024, 0, stream>>>(ebuf, gcnt, csr, offs, deg);
    k_agg1 <<<N_NODES / 4, 256, 0, stream>>>(offs, deg, csr, h1, al1s, al1d, b1, h1bg);
    k_mid  <<<(N_NODES + 63) / 64, 256, 0, stream>>>(h1bg, W2, a2s, a2d, h2, al2s, al2d);
    k_agg2 <<<N_NODES / 4, 256, 0, stream>>>(offs, deg, csr, h2, al2s, al2d, b2, hout);
    k_pool <<<NG, 256, 0, stream>>>(hout, batc, Wc, bc, out);
}

// Round 8
// 258.137 us; speedup vs baseline: 4.3119x; 1.1951x over previous
//
#include <hip/hip_runtime.h>
#include <hip/hip_fp16.h>
#include <hip/hip_fp8.h>

#define N_NODES 100000
#define N_EDGES 1600000
#define ET      (N_EDGES + N_NODES)   // 1,700,000
#define NG      512
#define SLOPE   0.2f

#define BKT_SHIFT 9                         // 512 nodes per bucket
#define NB_B   ((N_NODES + 511) / 512)      // 196 buckets
#define CHUNK_A 8192
#define NBLK_A ((ET + CHUNK_A - 1) / CHUNK_A)   // 208
#define H1B    ((N_NODES + 255) / 256)      // 391 mfma-h1 blocks (256 nodes each)

typedef _Float16 half8_t __attribute__((ext_vector_type(8)));
typedef float    f32x4_t __attribute__((ext_vector_type(4)));

// ---- fused: MFMA h1 = x@W1 (fp8 out) + logits  |  coarse bucket histogram ----
__global__ __launch_bounds__(256) void k_prep(
    const float* __restrict__ x, const float* __restrict__ W1,
    const float* __restrict__ a1s, const float* __restrict__ a1d,
    const int* __restrict__ ei,
    __hip_fp8_e4m3* __restrict__ h1, float* __restrict__ al1s, float* __restrict__ al1d,
    int* __restrict__ bsize)
{
    __shared__ float Wl[64 * 64];
    __shared__ float asf[64], adf[64];
    __shared__ int hcnt[NB_B];
    int tid = threadIdx.x;

    if (blockIdx.x >= H1B) {
        // ---------------- histogram role ----------------
        for (int i = tid; i < NB_B; i += 256) hcnt[i] = 0;
        __syncthreads();
        int base = (blockIdx.x - H1B) * CHUNK_A;
        int m = min(CHUNK_A, ET - base);
        for (int i = tid; i < m; i += 256) {
            int eid = base + i;
            int d = (eid < N_EDGES) ? ei[N_EDGES + eid] : (eid - N_EDGES);
            atomicAdd(&hcnt[d >> BKT_SHIFT], 1);
        }
        __syncthreads();
        for (int i = tid; i < NB_B; i += 256)
            if (hcnt[i]) atomicAdd(&bsize[i], hcnt[i]);
        return;
    }

    // ---------------- MFMA h1 role: 4 waves x 16 nodes x 4 iters ----------------
    for (int i = tid; i < 64 * 64; i += 256) Wl[i] = W1[i];
    if (tid < 64) { asf[tid] = a1s[tid]; adf[tid] = a1d[tid]; }
    __syncthreads();

    int wv = tid >> 6, lane = tid & 63;
    int m = lane & 15, q = lane >> 4;

    half8_t bf[4][2];
#pragma unroll
    for (int t = 0; t < 4; ++t)
#pragma unroll
        for (int s = 0; s < 2; ++s) {
            half8_t b;
#pragma unroll
            for (int j = 0; j < 8; ++j)
                b[j] = (_Float16)Wl[(s * 32 + q * 8 + j) * 64 + t * 16 + m];
            bf[t][s] = b;
        }

    for (int it = 0; it < 4; ++it) {
        int node0 = blockIdx.x * 256 + wv * 64 + it * 16;
        int node = node0 + m;
        half8_t av0 = {}, av1 = {};
        if (node < N_NODES) {
            const float4* xr = (const float4*)(x + (long long)node * 64);
            float4 p0 = xr[q * 2], p1 = xr[q * 2 + 1];
            float4 p2 = xr[q * 2 + 8], p3 = xr[q * 2 + 9];
            av0[0] = (_Float16)p0.x; av0[1] = (_Float16)p0.y;
            av0[2] = (_Float16)p0.z; av0[3] = (_Float16)p0.w;
            av0[4] = (_Float16)p1.x; av0[5] = (_Float16)p1.y;
            av0[6] = (_Float16)p1.z; av0[7] = (_Float16)p1.w;
            av1[0] = (_Float16)p2.x; av1[1] = (_Float16)p2.y;
            av1[2] = (_Float16)p2.z; av1[3] = (_Float16)p2.w;
            av1[4] = (_Float16)p3.x; av1[5] = (_Float16)p3.y;
            av1[6] = (_Float16)p3.z; av1[7] = (_Float16)p3.w;
        }
        f32x4_t acc[4] = {{0,0,0,0},{0,0,0,0},{0,0,0,0},{0,0,0,0}};
#pragma unroll
        for (int t = 0; t < 4; ++t) {
            acc[t] = __builtin_amdgcn_mfma_f32_16x16x32_f16(av0, bf[t][0], acc[t], 0, 0, 0);
            acc[t] = __builtin_amdgcn_mfma_f32_16x16x32_f16(av1, bf[t][1], acc[t], 0, 0, 0);
        }
#pragma unroll
        for (int r = 0; r < 4; ++r) {
            int nr = node0 + q * 4 + r;
            bool ok = nr < N_NODES;
#pragma unroll
            for (int t = 0; t < 4; ++t) {
                float v = acc[t][r];
                if (ok) h1[(long long)nr * 64 + t * 16 + m] = __hip_fp8_e4m3(v);
                float ps = v * asf[t * 16 + m];
                float pd = v * adf[t * 16 + m];
                ps += __shfl_xor(ps, 1); ps += __shfl_xor(ps, 2);
                ps += __shfl_xor(ps, 4); ps += __shfl_xor(ps, 8);
                pd += __shfl_xor(pd, 1); pd += __shfl_xor(pd, 2);
                pd += __shfl_xor(pd, 4); pd += __shfl_xor(pd, 8);
                if (ok && m == t) { al1s[nr * 4 + t] = ps; al1d[nr * 4 + t] = pd; }
            }
        }
    }
}

// ---------------- scan of bucket sizes (1 block) ----------------
__global__ __launch_bounds__(256) void k_scanB(const int* __restrict__ bsize,
                                               int* __restrict__ bbase, int* __restrict__ bcur)
{
    __shared__ int tmp[256];
    int tid = threadIdx.x;
    int v = (tid < NB_B) ? bsize[tid] : 0;
    tmp[tid] = v;
    __syncthreads();
    for (int off = 1; off < 256; off <<= 1) {
        int t = (tid >= off) ? tmp[tid - off] : 0;
        __syncthreads();
        tmp[tid] += t;
        __syncthreads();
    }
    if (tid < NB_B) { int e = tmp[tid] - v; bbase[tid] = e; bcur[tid] = e; }
}

// ---- pass A: LDS counting sort of 8K-edge chunks (1024 threads) ----
__global__ __launch_bounds__(1024) void k_passA(const int* __restrict__ ei,
                                                int* __restrict__ bcur, unsigned int* __restrict__ ebuf)
{
    __shared__ unsigned int stage[CHUNK_A];     // 32 KB
    __shared__ unsigned char sbin[CHUNK_A];     // 8 KB
    __shared__ int hist[NB_B];
    __shared__ int binst[NB_B];
    __shared__ int resv[NB_B];
    __shared__ int cur[NB_B];
    __shared__ int tmp[1024];
    int tid = threadIdx.x;
    int base = blockIdx.x * CHUNK_A;
    int m = min(CHUNK_A, ET - base);
    for (int i = tid; i < NB_B; i += 1024) hist[i] = 0;
    __syncthreads();
    for (int i = tid; i < m; i += 1024) {
        int eid = base + i;
        int d = (eid < N_EDGES) ? ei[N_EDGES + eid] : (eid - N_EDGES);
        atomicAdd(&hist[d >> BKT_SHIFT], 1);
    }
    __syncthreads();
    int v = (tid < NB_B) ? hist[tid] : 0;
    tmp[tid] = v;
    __syncthreads();
    for (int off = 1; off < 1024; off <<= 1) {
        int t = (tid >= off) ? tmp[tid - off] : 0;
        __syncthreads();
        tmp[tid] += t;
        __syncthreads();
    }
    if (tid < NB_B) {
        int e = tmp[tid] - v;
        binst[tid] = e;
        cur[tid] = e;
        resv[tid] = v ? atomicAdd(&bcur[tid], v) : 0;   // ~196 atomics / block
    }
    __syncthreads();
    for (int i = tid; i < m; i += 1024) {
        int eid = base + i;
        int s, d;
        if (eid < N_EDGES) { s = ei[eid]; d = ei[N_EDGES + eid]; }
        else               { s = eid - N_EDGES; d = s; }
        int b = d >> BKT_SHIFT;
        int pos = atomicAdd(&cur[b], 1);
        stage[pos] = ((unsigned int)(d & 511) << 17) | (unsigned int)s;
        sbin[pos] = (unsigned char)b;
    }
    __syncthreads();
    for (int i = tid; i < m; i += 1024) {
        int b = sbin[i];
        ebuf[resv[b] + (i - binst[b])] = stage[i];
    }
}

// ---- pass B: per-bucket node hist+scan + csr scatter (1024 threads) ----
__global__ __launch_bounds__(1024) void k_passB(
    const unsigned int* __restrict__ ebuf, const int* __restrict__ bbase,
    const int* __restrict__ bsize,
    int* __restrict__ csr, int* __restrict__ offs, int* __restrict__ deg)
{
    __shared__ int ldeg[512];
    __shared__ int lofs[512];
    __shared__ int lcur[512];
    int tid = threadIdx.x;
    int b = blockIdx.x;
    int nb0 = b << BKT_SHIFT;
    int nn = min(512, N_NODES - nb0);
    int gbase = bbase[b], cnt = bsize[b];
    if (tid < 512) ldeg[tid] = 0;
    __syncthreads();
    for (int i = tid; i < cnt; i += 1024)
        atomicAdd(&ldeg[ebuf[gbase + i] >> 17], 1);
    __syncthreads();
    int v = 0;
    if (tid < 512) { v = ldeg[tid]; lofs[tid] = v; }
    __syncthreads();
    for (int off = 1; off < 512; off <<= 1) {
        int t = (tid >= off && tid < 512) ? lofs[tid - off] : 0;
        __syncthreads();
        if (tid < 512) lofs[tid] += t;
        __syncthreads();
    }
    if (tid < 512) {
        int e = lofs[tid] - v;                  // exclusive
        lcur[tid] = e;
        if (tid < nn) { offs[nb0 + tid] = gbase + e; deg[nb0 + tid] = v; }
    }
    __syncthreads();
    for (int i = tid; i < cnt; i += 1024) {
        unsigned int ev = ebuf[gbase + i];
        int dl = ev >> 17, s = (int)(ev & 0x1FFFF);
        int p = atomicAdd(&lcur[dl], 1);
        csr[gbase + p] = s;
    }
}

// ---- layer 1 aggregate: WAVE = 4 NODES. Staged union of 4 contiguous csr ranges
//      (~68/64 lane utilization vs 17/64), consume = proven 4-edge x 16-lane loop
//      per node over masked sub-ranges. ----
__global__ __launch_bounds__(256) void k_agg1(
    const int* __restrict__ offs, const int* __restrict__ deg, const int* __restrict__ csr,
    const __hip_fp8_e4m3* __restrict__ h1, const float* __restrict__ al1s, const float* __restrict__ al1d,
    const float* __restrict__ b1, __half* __restrict__ h1bg)
{
    __shared__ int   sarr[4][64];       // s*64 (pre-scaled byte row offset)
    __shared__ float warr[4][4 * 72];   // [wave][head*72 + j]: conflict-free
    __shared__ __align__(16) float h1b[4][4][64];
    int tid = threadIdx.x;
    int wv = tid >> 6, lane = tid & 63;
    int eslot = lane >> 4;              // which of 4 edges per iteration
    int cq = lane & 15;                 // channel quad: channels 4cq..4cq+3
    int h = cq >> 2;                    // head of this channel quad
    int cq4 = cq * 4;
    int node0 = (blockIdx.x * 4 + wv) * 4;
    // 4 consecutive nodes: csr ranges contiguous (groups of 4 never straddle a bucket)
    int dg0 = deg[node0], dg1 = deg[node0 + 1], dg2 = deg[node0 + 2], dg3 = deg[node0 + 3];
    int st0 = offs[node0];
    int e1 = dg0, e2 = e1 + dg1, e3 = e2 + dg2, D = e3 + dg3;
    float bias = b1[lane];              // coalesced, L1-hot
    const char* __restrict__ h1c = (const char*)h1;

    float A0[4] = {0,0,0,0}, A1[4] = {0,0,0,0}, A2[4] = {0,0,0,0}, A3[4] = {0,0,0,0};
    float DN[4] = {0,0,0,0};
    for (int base = 0; base < D; base += 64) {
        int m = min(64, D - base);
        int s = 0;
        float w0 = 0.f, w1 = 0.f, w2 = 0.f, w3 = 0.f;
        if (lane < m) {
            int e = base + lane;
            s = csr[st0 + e];                       // coalesced
            int nid = (e >= e1) + (e >= e2) + (e >= e3);
            const float4 as4 = *(const float4*)(al1s + s * 4);              // 16B gather
            const float4 ad4 = *(const float4*)(al1d + (node0 + nid) * 4);  // L1-hot, 4 rows
            float q0 = as4.x + ad4.x; q0 = q0 > 0.f ? q0 : SLOPE * q0;
            float q1 = as4.y + ad4.y; q1 = q1 > 0.f ? q1 : SLOPE * q1;
            float q2 = as4.z + ad4.z; q2 = q2 > 0.f ? q2 : SLOPE * q2;
            float q3 = as4.w + ad4.w; q3 = q3 > 0.f ? q3 : SLOPE * q3;
            w0 = __expf(q0); w1 = __expf(q1); w2 = __expf(q2); w3 = __expf(q3);
        }
        sarr[wv][lane] = s << 6;                    // pad lanes: s=0, w=0
        warr[wv][0 * 72 + lane] = w0;
        warr[wv][1 * 72 + lane] = w1;
        warr[wv][2 * 72 + lane] = w2;
        warr[wv][3 * 72 + lane] = w3;
        // intra-wave LDS dependency only — no barrier
        int lo = base, hi = base + m;
#pragma unroll
        for (int nid = 0; nid < 4; ++nid) {
            int jb = (nid == 0) ? 0  : ((nid == 1) ? e1 : ((nid == 2) ? e2 : e3));
            int je = (nid == 0) ? e1 : ((nid == 1) ? e2 : ((nid == 2) ? e3 : D));
            int js = jb > lo ? jb : lo;             // wave-uniform bounds
            int jeX = je < hi ? je : hi;
            if (js < jeX) {
                int jend = jeX - base;
                for (int j0 = (js - base) & ~3; j0 < jend; j0 += 4) {
                    int j = j0 + eslot;
                    int jc = j < 63 ? j : 63;       // clamp LDS index (wgt masked anyway)
                    int jg = base + j;
                    bool okv = (jg >= js) && (jg < jeX);
                    float wgt = warr[wv][h * 72 + jc];
                    wgt = okv ? wgt : 0.f;
                    int off = sarr[wv][jc] + cq4;   // 4-addr broadcast + add
                    unsigned int pk = *(const unsigned int*)(h1c + off);  // 64B/edge
                    A0[nid] = fmaf(wgt, __builtin_amdgcn_cvt_f32_fp8(pk, 0), A0[nid]);
                    A1[nid] = fmaf(wgt, __builtin_amdgcn_cvt_f32_fp8(pk, 1), A1[nid]);
                    A2[nid] = fmaf(wgt, __builtin_amdgcn_cvt_f32_fp8(pk, 2), A2[nid]);
                    A3[nid] = fmaf(wgt, __builtin_amdgcn_cvt_f32_fp8(pk, 3), A3[nid]);
                    DN[nid] += wgt;
                }
            }
        }
    }
    // epilogue per node: reduce over 4 edge-slots, normalize + bias + ELU, store
#pragma unroll
    for (int nid = 0; nid < 4; ++nid) {
        float x0 = A0[nid], x1 = A1[nid], x2 = A2[nid], x3 = A3[nid], dn = DN[nid];
        x0 += __shfl_xor(x0, 16); x0 += __shfl_xor(x0, 32);
        x1 += __shfl_xor(x1, 16); x1 += __shfl_xor(x1, 32);
        x2 += __shfl_xor(x2, 16); x2 += __shfl_xor(x2, 32);
        x3 += __shfl_xor(x3, 16); x3 += __shfl_xor(x3, 32);
        dn += __shfl_xor(dn, 16); dn += __shfl_xor(dn, 32);
        if (lane < 16)
            *(float4*)&h1b[wv][nid][cq4] = make_float4(x0, x1, x2, x3);
        float denc = __shfl(dn, (lane >> 4) << 2);  // head lane>>4's den on lane 4h
        // intra-wave LDS, no barrier
        float v = h1b[wv][nid][lane] / (denc + 1e-16f) + bias;
        v = v > 0.f ? v : __expf(v) - 1.f;  // fast ELU
        h1bg[(long long)(node0 + nid) * 64 + lane] = __float2half_rn(v);  // coalesced
    }
}

// ---- MFMA: h2 = h1b @ W2 (fp16 out) + layer-2 logits. 16 nodes/wave ----
__global__ __launch_bounds__(256) void k_mid(
    const __half* __restrict__ h1bg, const float* __restrict__ W2,
    const float* __restrict__ a2s, const float* __restrict__ a2d,
    __half* __restrict__ h2, float* __restrict__ al2s, float* __restrict__ al2d)
{
    __shared__ float W2l[64 * 16];
    int tid = threadIdx.x;
    for (int i = tid; i < 64 * 16; i += 256) W2l[i] = W2[i];
    __syncthreads();
    int wv = tid >> 6, lane = tid & 63;
    int m = lane & 15, q = lane >> 4;
    // B-frag: lane holds B[k = s*32 + q*8 + j][n = m]
    half8_t bf[2];
#pragma unroll
    for (int s = 0; s < 2; ++s) {
        half8_t b;
#pragma unroll
        for (int j = 0; j < 8; ++j)
            b[j] = (_Float16)W2l[(s * 32 + q * 8 + j) * 16 + m];
        bf[s] = b;
    }
    int node0 = blockIdx.x * 64 + wv * 16;
    half8_t av0 = {}, av1 = {};
    if (node0 + m < N_NODES) {
        const __half* ar = h1bg + (long long)(node0 + m) * 64;
        av0 = *(const half8_t*)(ar + q * 8);        // 16B coalesced
        av1 = *(const half8_t*)(ar + 32 + q * 8);
    }
    f32x4_t acc = {0, 0, 0, 0};
    acc = __builtin_amdgcn_mfma_f32_16x16x32_f16(av0, bf[0], acc, 0, 0, 0);
    acc = __builtin_amdgcn_mfma_f32_16x16x32_f16(av1, bf[1], acc, 0, 0, 0);
    float a2sm = a2s[m], a2dm = a2d[m];
    // C: col=m (h2 channel), row=q*4+r (node within tile)
#pragma unroll
    for (int r = 0; r < 4; ++r) {
        int nr = node0 + q * 4 + r;
        bool ok = nr < N_NODES;
        float v = acc[r];
        if (ok) h2[nr * 16 + m] = __float2half_rn(v);
        float ps = v * a2sm, pd = v * a2dm;
        ps += __shfl_xor(ps, 1); ps += __shfl_xor(ps, 2);
        ps += __shfl_xor(ps, 4); ps += __shfl_xor(ps, 8);
        pd += __shfl_xor(pd, 1); pd += __shfl_xor(pd, 2);
        pd += __shfl_xor(pd, 4); pd += __shfl_xor(pd, 8);
        if (ok && m == 0) { al2s[nr] = ps; al2d[nr] = pd; }
    }
}

// ---- layer 2 aggregate: WAVE = 4 NODES, staged union, 8-edge x 8-lane consume ----
__global__ __launch_bounds__(256) void k_agg2(
    const int* __restrict__ offs, const int* __restrict__ deg, const int* __restrict__ csr,
    const __half* __restrict__ h2, const float* __restrict__ al2s, const float* __restrict__ al2d,
    const float* __restrict__ b2, float* __restrict__ hout)
{
    __shared__ int   sarr[4][64];
    __shared__ float warr[4][64];
    int tid = threadIdx.x;
    int wv = tid >> 6, lane = tid & 63;
    int ec = lane >> 3, cc = lane & 7;  // 8 edges x 8 channel-pairs
    int node0 = (blockIdx.x * 4 + wv) * 4;
    int dg0 = deg[node0], dg1 = deg[node0 + 1], dg2 = deg[node0 + 2], dg3 = deg[node0 + 3];
    int st0 = offs[node0];
    int e1 = dg0, e2 = e1 + dg1, e3 = e2 + dg2, D = e3 + dg3;
    const __half2* __restrict__ h2v = (const __half2*)h2;

    float A0[4] = {0,0,0,0}, A1[4] = {0,0,0,0}, DN[4] = {0,0,0,0};
    for (int base = 0; base < D; base += 64) {
        int m = min(64, D - base);
        int s = 0; float wl = 0.f;
        if (lane < m) {
            int e = base + lane;
            s = csr[st0 + e];                       // coalesced
            int nid = (e >= e1) + (e >= e2) + (e >= e3);
            float q = al2s[s] + al2d[node0 + nid];  // gathers (L2-resident)
            q = q > 0.f ? q : SLOPE * q;
            wl = __expf(q);
        }
        sarr[wv][lane] = s;                         // pad: s=0, w=0
        warr[wv][lane] = wl;
        // intra-wave LDS dependency only — no barrier
        int lo = base, hi = base + m;
#pragma unroll
        for (int nid = 0; nid < 4; ++nid) {
            int jb = (nid == 0) ? 0  : ((nid == 1) ? e1 : ((nid == 2) ? e2 : e3));
            int je = (nid == 0) ? e1 : ((nid == 1) ? e2 : ((nid == 2) ? e3 : D));
            int js = jb > lo ? jb : lo;
            int jeX = je < hi ? je : hi;
            if (js < jeX) {
                int jend = jeX - base;
                for (int j0 = (js - base) & ~7; j0 < jend; j0 += 8) {
                    int j = j0 + ec;
                    int jc = j < 63 ? j : 63;
                    int jg = base + j;
                    bool okv = (jg >= js) && (jg < jeX);
                    float wgt = warr[wv][jc];
                    wgt = okv ? wgt : 0.f;
                    int s2i = sarr[wv][jc];         // 8-addr broadcast
                    __half2 hv = h2v[s2i * 8 + cc]; // 32B row, 8 rows in flight
                    A0[nid] = fmaf(__low2float(hv),  wgt, A0[nid]);
                    A1[nid] = fmaf(__high2float(hv), wgt, A1[nid]);
                    DN[nid] += wgt;                 // each edge once per cc-lane
                }
            }
        }
    }
    // epilogue per node: xor 8/16/32 completes a0,a1,den; normalize + ELU; store
#pragma unroll
    for (int nid = 0; nid < 4; ++nid) {
        float x0 = A0[nid], x1 = A1[nid], dn = DN[nid];
        x0 += __shfl_xor(x0, 8);  x1 += __shfl_xor(x1, 8);  dn += __shfl_xor(dn, 8);
        x0 += __shfl_xor(x0, 16); x1 += __shfl_xor(x1, 16); dn += __shfl_xor(dn, 16);
        x0 += __shfl_xor(x0, 32); x1 += __shfl_xor(x1, 32); dn += __shfl_xor(dn, 32);
        if (lane < 8) {
            float inv = 1.f / (dn + 1e-16f);
            float v0 = x0 * inv + b2[2 * cc];
            float v1 = x1 * inv + b2[2 * cc + 1];
            v0 = v0 > 0.f ? v0 : __expf(v0) - 1.f;  // fast ELU
            v1 = v1 > 0.f ? v1 : __expf(v1) - 1.f;
            ((float2*)hout)[(node0 + nid) * 8 + cc] = make_float2(v0, v1);  // coalesced
        }
    }
}

// ---- mean-pool per graph (binary-search node range) + classifier ----
__global__ __launch_bounds__(256) void k_pool(
    const float* __restrict__ hout, const int* __restrict__ batch,
    const float* __restrict__ Wc, const float* __restrict__ bc, float* __restrict__ out)
{
    __shared__ float red[16][17];
    __shared__ int bnd[2];
    int g = blockIdx.x;
    int t = threadIdx.x, c = t & 15, slot = t >> 4;
    if (t < 2) {
        int key = g + t;                // lower_bound(batch, g) and (g+1)
        int lo = 0, hi = N_NODES;
        while (lo < hi) { int mid = (lo + hi) >> 1; if (batch[mid] < key) lo = mid + 1; else hi = mid; }
        bnd[t] = lo;
    }
    __syncthreads();
    int s = bnd[0], e = bnd[1];
    float sum = 0.f;
    for (int n = s + slot; n < e; n += 16)
        sum += hout[n * 16 + c];        // fully coalesced (1 KB / iter / block)
    red[slot][c] = sum;
    __syncthreads();
    if (t < 16) {
        float tot = 0.f;
#pragma unroll
        for (int k = 0; k < 16; ++k) tot += red[k][t];
        float cnt = fmaxf((float)(e - s), 1.0f);
        float pc = (tot / cnt) * Wc[t];
        pc += __shfl_xor(pc, 1); pc += __shfl_xor(pc, 2);
        pc += __shfl_xor(pc, 4); pc += __shfl_xor(pc, 8);
        if (t == 0) out[g] = pc + bc[0];
    }
}

extern "C" void kernel_launch(void* const* d_in, const int* in_sizes, int n_in,
                              void* d_out, int out_size, void* d_ws, size_t ws_size,
                              hipStream_t stream)
{
    const float* x    = (const float*)d_in[0];
    const int*   ei   = (const int*)d_in[1];
    const int*   batc = (const int*)d_in[2];
    const float* W1   = (const float*)d_in[3];
    const float* a1s  = (const float*)d_in[4];
    const float* a1d  = (const float*)d_in[5];
    const float* b1   = (const float*)d_in[6];
    const float* W2   = (const float*)d_in[7];
    const float* a2s  = (const float*)d_in[8];
    const float* a2d  = (const float*)d_in[9];
    const float* b2   = (const float*)d_in[10];
    const float* Wc   = (const float*)d_in[11];
    const float* bc   = (const float*)d_in[12];
    float* out = (float*)d_out;

    // ---- workspace carve, 16B-aligned chunks. Zero region first, one memset. ----
    char* ws = (char*)d_ws;
    size_t off = 0;
    auto carveB = [&](size_t bytes) {
        void* p = ws + off;
        off += ((bytes + 15) & ~(size_t)15);
        return p;
    };
    auto carve = [&](size_t elems) { return carveB(elems * 4); };
    int*   bsize  = (int*)  carve(NB_B);           // zeroed
    size_t zero_bytes = off;
    int*   bbase  = (int*)  carve(NB_B);
    int*   bcur   = (int*)  carve(NB_B);
    unsigned int* ebuf = (unsigned int*)carve(ET);
    int*   csr    = (int*)  carve(ET);
    int*   offs   = (int*)  carve(N_NODES);
    int*   deg    = (int*)  carve(N_NODES);
    __hip_fp8_e4m3* h1 = (__hip_fp8_e4m3*)carveB((size_t)N_NODES * 64);
    float* al1s   = (float*)carve((size_t)N_NODES * 4);
    float* al1d   = (float*)carve((size_t)N_NODES * 4);
    __half* h1bg  = (__half*)carveB((size_t)N_NODES * 64 * 2);
    __half* h2    = (__half*)carveB((size_t)N_NODES * 16 * 2);
    float* al2s   = (float*)carve(N_NODES);
    float* al2d   = (float*)carve(N_NODES);
    float* hout   = (float*)carve((size_t)N_NODES * 16);

    hipMemsetAsync(d_ws, 0, zero_bytes, stream);

    k_prep <<<H1B + NBLK_A, 256, 0, stream>>>(x, W1, a1s, a1d, ei, h1, al1s, al1d, bsize);
    k_scanB<<<1, 256, 0, stream>>>(bsize, bbase, bcur);
    k_passA<<<NBLK_A, 1024, 0, stream>>>(ei, bcur, ebuf);
    k_passB<<<NB_B, 1024, 0, stream>>>(ebuf, bbase, bsize, csr, offs, deg);
    k_agg1 <<<N_NODES / 16, 256, 0, stream>>>(offs, deg, csr, h1, al1s, al1d, b1, h1bg);
    k_mid  <<<(N_NODES + 63) / 64, 256, 0, stream>>>(h1bg, W2, a2s, a2d, h2, al2s, al2d);
    k_agg2 <<<N_NODES / 16, 256, 0, stream>>>(offs, deg, csr, h2, al2s, al2d, b2, hout);
    k_pool <<<NG, 256, 0, stream>>>(hout, batc, Wc, bc, out);
}